// Round 8
// baseline (199.119 us; speedup 1.0000x reference)
//
#include <hip/hip_runtime.h>

// Problem shape (fixed by the reference setup_inputs)
constexpr int B = 16, F = 16, H = 256, W = 256;
constexpr int HW = H * W;               // 65536
constexpr int SPATIAL = B * HW;         // 1,048,576 per-feature element count
constexpr int PLANE4 = HW / 4;          // 16384 float4 (or mask-dwords) per (b,f) plane
constexpr int BSTRIDE4 = F * PLANE4;    // 262144 per batch index

constexpr int NBLK = 1024;              // 2 blocks/CU (LDS-bound), 2 generations
constexpr int NTHREADS = 256;           // 4 waves/block; wave w owns features 4w..4w+3
constexpr int NWAVES = NTHREADS / 64;
constexpr int G = 4;                    // iterations; block covers G*64 columns
static_assert(NBLK * G * 64 == B * PLANE4, "coverage must be exact");

constexpr int NVALS = 50;               // s[16], c[16], dtot[16], sall, call
constexpr int WBUF = 9216;              // per-wave per-buffer: 4KB inp + 4KB tgt + 1KB msk

// R16: VGPR-boundedness experiment. Seven schedule variants (ILP 1-24, 512-2048
// blocks, strided vs contiguous) all pin at ~2.55 TB/s: the shared invariant is
// global->VGPR loads, whose in-flight bytes are capped by the register file
// (and the compiler refuses >~12 live loads regardless of fences — R12/R14
// VGPR counts proved it). global_load_lds DMAs to LDS with ZERO VGPR
// destinations -> outstanding-request depth becomes LDS-bound (72KB/block).
// Counted vmcnt(12) (never 0 in steady state) + raw s_barrier keep the
// prefetch alive across barriers (avoids __syncthreads' vmcnt(0) drain).
// All vmem is builtin-issued, so the vmcnt counts are exact.
// Falsification: if this ALSO lands at ~56us, the ~2.55 TB/s is a downstream
// path ceiling for this working set -> declare roofline.

__device__ __forceinline__ void g2l16(const float4* g, void* l) {
    __builtin_amdgcn_global_load_lds((__attribute__((address_space(1))) void*)g,
                                     (__attribute__((address_space(3))) void*)l,
                                     16, 0, 0);
}
__device__ __forceinline__ void g2l4(const unsigned int* g, void* l) {
    __builtin_amdgcn_global_load_lds((__attribute__((address_space(1))) void*)g,
                                     (__attribute__((address_space(3))) void*)l,
                                     4, 0, 0);
}

__global__ __launch_bounds__(NTHREADS) void heatloss_main(
        const float4* __restrict__ inp, const float4* __restrict__ tgt,
        const unsigned int* __restrict__ msk, float* __restrict__ partials) {
    // Per wave, per buffer: [0,4096) inp (4 planes x 1KB), [4096,8192) tgt,
    // [8192,9216) masks (4 planes x 256B). Double-buffered.
    __shared__ __align__(16) unsigned char lds[NWAVES][2][WBUF];
    __shared__ float red[NWAVES][14];

    const int tid  = threadIdx.x;
    const int wave = tid >> 6;
    const int lane = tid & 63;
    const int foff = (wave * 4) * PLANE4;

    // Block covers a contiguous 256-column run: base aligned to 256, PLANE4
    // divisible by 256 -> batch index b and plane residency constant per block.
    const int run0 = blockIdx.x * (G * 64);
    const int b    = run0 >> 14;                    // run0 / PLANE4
    const int hw40 = run0 & (PLANE4 - 1);
    const int gbase = b * BSTRIDE4 + foff + hw40 + lane;   // per-lane
    const float4*       ga = inp + gbase;
    const float4*       gt = tgt + gbase;
    const unsigned int* gm = msk + gbase;

    float s[4]  = {0.f, 0.f, 0.f, 0.f};
    float c[4]  = {0.f, 0.f, 0.f, 0.f};
    float dt[4] = {0.f, 0.f, 0.f, 0.f};
    float sall = 0.f, call = 0.f;

    // stage(t): 12 DMA instructions into lds[wave][buf] (wave-uniform dest
    // base; HW scatters lane*size). Global src per-lane, contiguous.
    auto stage = [&](int t, int buf) {
        unsigned char* dst = &lds[wave][buf][0];
        const int off = t * 64;
        #pragma unroll
        for (int j = 0; j < 4; j++) g2l16(ga + off + j * PLANE4, dst + j * 1024);
        #pragma unroll
        for (int j = 0; j < 4; j++) g2l16(gt + off + j * PLANE4, dst + 4096 + j * 1024);
        #pragma unroll
        for (int j = 0; j < 4; j++) g2l4 (gm + off + j * PLANE4, dst + 8192 + j * 256);
    };

    auto consume = [&](int buf) {
        // any over all 16 features: read every wave's staged mask planes.
        // lane*4 byte offsets -> 2 lanes/bank (free).
        unsigned int any = 0u;
        #pragma unroll
        for (int w2 = 0; w2 < 4; w2++)
            #pragma unroll
            for (int j = 0; j < 4; j++)
                any |= *(const unsigned int*)&lds[w2][buf][8192 + j * 256 + lane * 4];

        const float af0 = (any & 0x000000FFu) ? 1.f : 0.f;
        const float af1 = (any & 0x0000FF00u) ? 1.f : 0.f;
        const float af2 = (any & 0x00FF0000u) ? 1.f : 0.f;
        const float af3 = (any & 0xFF000000u) ? 1.f : 0.f;
        if (wave == 0) call += (af0 + af1) + (af2 + af3);  // count each pixel once

        #pragma unroll
        for (int j = 0; j < 4; j++) {
            const float4 a  = *(const float4*)&lds[wave][buf][j * 1024 + lane * 16];
            const float4 t4 = *(const float4*)&lds[wave][buf][4096 + j * 1024 + lane * 16];
            const unsigned int mm =
                *(const unsigned int*)&lds[wave][buf][8192 + j * 256 + lane * 4];
            const float d0 = fabsf(a.x - t4.x);
            const float d1 = fabsf(a.y - t4.y);
            const float d2 = fabsf(a.z - t4.z);
            const float d3 = fabsf(a.w - t4.w);
            const float m0 = (float)( mm        & 0xFFu);
            const float m1 = (float)((mm >> 8)  & 0xFFu);
            const float m2 = (float)((mm >> 16) & 0xFFu);
            const float m3 = (float)( mm >> 24);
            dt[j] += (d0 + d1) + (d2 + d3);
            s[j]  += m0 * d0 + m1 * d1 + m2 * d2 + m3 * d3;
            c[j]  += (m0 + m1) + (m2 + m3);
            sall  += af0 * d0 + af1 * d1 + af2 * d2 + af3 * d3;
        }
    };

    stage(0, 0);                           // 12 in flight
    #pragma unroll
    for (int t = 0; t < G; ++t) {
        if (t + 1 < G) {
            stage(t + 1, (t + 1) & 1);     // +12 -> 24 in flight
            asm volatile("s_waitcnt vmcnt(12)" ::: "memory");  // stage(t) done
        } else {
            asm volatile("s_waitcnt vmcnt(0)" ::: "memory");
        }
        __builtin_amdgcn_s_barrier();      // B1: all waves' buf-t staged
        consume(t & 1);
        if (t + 1 < G) {
            asm volatile("" ::: "memory"); // pin consume's LDS reads above B2
            __builtin_amdgcn_s_barrier();  // B2: buf[t&1] free for stage(t+2)
        }
    }

    // Full-wave (width 64) reduction; each wave owns disjoint features.
    #pragma unroll
    for (int j = 0; j < 4; j++) {
        float xs = s[j], xc = c[j], xd = dt[j];
        #pragma unroll
        for (int o = 32; o > 0; o >>= 1) {
            xs += __shfl_down(xs, o, 64);
            xc += __shfl_down(xc, o, 64);
            xd += __shfl_down(xd, o, 64);
        }
        if (lane == 0) {
            red[wave][0 + j] = xs;
            red[wave][4 + j] = xc;
            red[wave][8 + j] = xd;
        }
    }
    float xa = sall, xcl = call;
    #pragma unroll
    for (int o = 32; o > 0; o >>= 1) {
        xa  += __shfl_down(xa,  o, 64);
        xcl += __shfl_down(xcl, o, 64);
    }
    if (lane == 0) { red[wave][12] = xa; red[wave][13] = xcl; }
    __syncthreads();

    if (tid < NVALS) {
        float t;
        if (tid < 16) {
            t = red[tid >> 2][0 + (tid & 3)];
        } else if (tid < 32) {
            const int f = tid - 16;
            t = red[f >> 2][4 + (f & 3)];
        } else if (tid < 48) {
            const int f = tid - 32;
            t = red[f >> 2][8 + (f & 3)];
        } else if (tid == 48) {
            t = (red[0][12] + red[1][12]) + (red[2][12] + red[3][12]);
        } else {
            t = (red[0][13] + red[1][13]) + (red[2][13] + red[3][13]);
        }
        partials[tid * NBLK + blockIdx.x] = t;  // layout [50][NBLK]
    }
}

// Finalize: one block sums the 50x1024 partials and emits the loss.
__global__ __launch_bounds__(NTHREADS) void heatloss_final(
        const float* __restrict__ partials, float* __restrict__ out) {
    const int tid  = threadIdx.x;
    const int wave = tid >> 6;
    const int lane = tid & 63;
    __shared__ float vals[NVALS];
    for (int v = wave; v < NVALS; v += NWAVES) {
        const float* p = partials + v * NBLK;
        float x = 0.f;
        #pragma unroll
        for (int k = 0; k < NBLK / 64; k++) x += p[lane + k * 64];
        #pragma unroll
        for (int o = 32; o > 0; o >>= 1) x += __shfl_down(x, o, 64);
        if (lane == 0) vals[v] = x;
    }
    __syncthreads();
    if (tid == 0) {
        const float Nf = (float)SPATIAL;
        float lf = 0.f, lbg = 0.f;
        #pragma unroll
        for (int f = 0; f < F; f++) {
            const float sf = vals[f], cf = vals[16 + f], dtf = vals[32 + f];
            lf += (cf > 0.f) ? sf / cf : 0.f;
            const float sbg = dtf - sf, cbg = Nf - cf;
            lbg += (cbg > 0.f) ? sbg / cbg : 0.f;
        }
        const float sa = vals[48], cl = vals[49];
        const float lall = (cl > 0.f) ? sa / cl : 0.f;  // == mean_f(sa_f/call)*16
        out[0] = (lf / 16.f + lbg / 16.f + lall / 16.f) / 3.f;
    }
}

extern "C" void kernel_launch(void* const* d_in, const int* in_sizes, int n_in,
                              void* d_out, int out_size, void* d_ws, size_t ws_size,
                              hipStream_t stream) {
    const float4*       inp = (const float4*)d_in[0];
    const float4*       tgt = (const float4*)d_in[1];
    const unsigned int* msk = (const unsigned int*)d_in[2];   // jnp.bool_ -> 1 byte each
    float* out      = (float*)d_out;
    float* partials = (float*)d_ws;                  // [50][1024] = 200 KB

    heatloss_main<<<NBLK, NTHREADS, 0, stream>>>(inp, tgt, msk, partials);
    heatloss_final<<<1, NTHREADS, 0, stream>>>(partials, out);
}

// Round 9
// 188.296 us; speedup vs baseline: 1.0575x; 1.0575x over previous
//
#include <hip/hip_runtime.h>

// Problem shape (fixed by the reference setup_inputs)
constexpr int B = 16, F = 16, H = 256, W = 256;
constexpr int HW = H * W;               // 65536
constexpr int SPATIAL = B * HW;         // 1,048,576 spatial locations
constexpr int NBLOCKS = 2048;
constexpr int NTHREADS = 512;           // 8 waves/block
constexpr int NVALS = 65;               // s[16], c[16], dtot[16], sall[16], call
constexpr int PLANE4 = HW / 4;          // 16384 float4 (or mask-dwords) per (b,f) plane
constexpr int BSTRIDE4 = F * PLANE4;    // 262144 per batch index
constexpr int FQ = 4;                   // features per quarter-wave

// R17 (final): revert to the R0 main kernel VERBATIM (best measured: 56.7us;
// eight alternative schedules — ILP 1/12/24-deep, VGPR vs LDS-DMA destination,
// 512/1024/2048 blocks, strided vs contiguous — all landed 56-97us; the
// ~2.55 TB/s delivered plateau is this op's machine ceiling on MI355X).
// Only change vs R0: the 65-block reduce + combine pair is merged into ONE
// 1024-thread finalize block (R12 measured the 2-dispatch structure's
// non-main overhead at 122us vs R0's 129us with its 65us main; this pairs
// the 2-dispatch tail with the 56.7us main, the one untested combination).
__global__ __launch_bounds__(NTHREADS, 6) void heatloss_main(
        const float4* __restrict__ inp, const float4* __restrict__ tgt,
        const unsigned int* __restrict__ msk, float* __restrict__ partials) {
    const int tid  = threadIdx.x;
    const int wave = tid >> 6;               // 0..7
    const int lane = tid & 63;
    const int l16  = lane & 15;
    const int q    = lane >> 4;              // quarter: features q*4 .. q*4+3
    const int g    = (blockIdx.x * 8 + wave) * 16 + l16;   // float4-group id
    const int b    = g >> 14;                // g / PLANE4
    const int hw4  = g & (PLANE4 - 1);
    const int base = b * BSTRIDE4 + hw4 + q * (FQ * PLANE4);

    unsigned int m[FQ];
    #pragma unroll
    for (int j = 0; j < FQ; j++) m[j] = msk[base + j * PLANE4];
    float4 av[FQ], tv[FQ];
    #pragma unroll
    for (int j = 0; j < FQ; j++) av[j] = inp[base + j * PLANE4];
    #pragma unroll
    for (int j = 0; j < FQ; j++) tv[j] = tgt[base + j * PLANE4];

    unsigned int anyu = m[0] | m[1] | m[2] | m[3];
    anyu |= __shfl_xor(anyu, 16, 64);        // combine quarters...
    anyu |= __shfl_xor(anyu, 32, 64);        // ...-> any over all 16 features
    const float af0 = (anyu & 0x000000FFu) ? 1.f : 0.f;
    const float af1 = (anyu & 0x0000FF00u) ? 1.f : 0.f;
    const float af2 = (anyu & 0x00FF0000u) ? 1.f : 0.f;
    const float af3 = (anyu & 0xFF000000u) ? 1.f : 0.f;
    const float call = (q == 0) ? (af0 + af1) + (af2 + af3) : 0.f;  // count once

    float s[FQ], c[FQ], dtot[FQ], sall[FQ];
    #pragma unroll
    for (int j = 0; j < FQ; j++) {
        const float4 a = av[j];
        const float4 t = tv[j];
        const float d0 = fabsf(a.x - t.x);
        const float d1 = fabsf(a.y - t.y);
        const float d2 = fabsf(a.z - t.z);
        const float d3 = fabsf(a.w - t.w);
        const unsigned int mm = m[j];
        const float m0 = (float)( mm        & 0xFFu);
        const float m1 = (float)((mm >> 8)  & 0xFFu);
        const float m2 = (float)((mm >> 16) & 0xFFu);
        const float m3 = (float)( mm >> 24);
        dtot[j] = (d0 + d1) + (d2 + d3);
        s[j]    = m0 * d0 + m1 * d1 + m2 * d2 + m3 * d3;
        c[j]    = (m0 + m1) + (m2 + m3);
        sall[j] = af0 * d0 + af1 * d1 + af2 * d2 + af3 * d3;
    }

    // Width-16 reduction (quarters hold disjoint features), LDS across waves.
    __shared__ float red[NTHREADS / 64][NVALS];
    const int fbase = q * FQ;
    #pragma unroll
    for (int j = 0; j < FQ; j++) {
        float xs = s[j], xc = c[j], xd = dtot[j], xa = sall[j];
        #pragma unroll
        for (int o = 8; o > 0; o >>= 1) {
            xs += __shfl_down(xs, o, 16);
            xc += __shfl_down(xc, o, 16);
            xd += __shfl_down(xd, o, 16);
            xa += __shfl_down(xa, o, 16);
        }
        if (l16 == 0) {
            red[wave][ 0 + fbase + j] = xs;
            red[wave][16 + fbase + j] = xc;
            red[wave][32 + fbase + j] = xd;
            red[wave][48 + fbase + j] = xa;
        }
    }
    float xcall = call;
    #pragma unroll
    for (int o = 8; o > 0; o >>= 1) xcall += __shfl_down(xcall, o, 16);
    if (lane == 0) red[wave][64] = xcall;
    __syncthreads();
    if (tid < NVALS) {
        float t = 0.f;
        #pragma unroll
        for (int w2 = 0; w2 < NTHREADS / 64; w2++) t += red[w2][tid];
        partials[tid * NBLOCKS + blockIdx.x] = t;   // layout [65][NBLOCKS]
    }
}

// Single finalize block: 16 waves; wave w strides values w, w+16, w+32, w+48
// (and 64 for w==0). Each value = 2048 partials pulled with 32 coalesced
// loads/lane (independent, unrolled -> deep ILP), wave-reduced, then one
// thread combines the 65 sums into the loss.
__global__ __launch_bounds__(1024) void heatloss_final(
        const float* __restrict__ partials, float* __restrict__ out) {
    const int tid  = threadIdx.x;
    const int wave = tid >> 6;               // 0..15
    const int lane = tid & 63;
    __shared__ float vals[NVALS];
    for (int v = wave; v < NVALS; v += 16) {
        const float* p = partials + v * NBLOCKS;
        float x = 0.f;
        #pragma unroll
        for (int k = 0; k < NBLOCKS / 64; k++) x += p[lane + k * 64];
        #pragma unroll
        for (int o = 32; o > 0; o >>= 1) x += __shfl_down(x, o, 64);
        if (lane == 0) vals[v] = x;
    }
    __syncthreads();
    if (tid == 0) {
        const float Nf = (float)SPATIAL;  // per-feature element count (B*H*W)
        const float call = vals[64];
        float lf = 0.f, lbg = 0.f, lall = 0.f;
        #pragma unroll
        for (int f = 0; f < F; f++) {
            const float sf = vals[f], cf = vals[16 + f];
            const float dt = vals[32 + f], sa = vals[48 + f];
            lf += (cf > 0.f) ? sf / cf : 0.f;
            const float sbg = dt - sf, cbg = Nf - cf;
            lbg += (cbg > 0.f) ? sbg / cbg : 0.f;
            lall += (call > 0.f) ? sa / call : 0.f;
        }
        out[0] = (lf / 16.f + lbg / 16.f + lall / 16.f) / 3.f;
    }
}

extern "C" void kernel_launch(void* const* d_in, const int* in_sizes, int n_in,
                              void* d_out, int out_size, void* d_ws, size_t ws_size,
                              hipStream_t stream) {
    const float4*       inp = (const float4*)d_in[0];
    const float4*       tgt = (const float4*)d_in[1];
    const unsigned int* msk = (const unsigned int*)d_in[2];   // jnp.bool_ -> 1 byte each
    float* out      = (float*)d_out;
    float* partials = (float*)d_ws;                  // [65][2048] = 532 KB

    heatloss_main<<<NBLOCKS, NTHREADS, 0, stream>>>(inp, tgt, msk, partials);
    heatloss_final<<<1, 1024, 0, stream>>>(partials, out);
}